// Round 4
// baseline (543.391 us; speedup 1.0000x reference)
//
#include <hip/hip_runtime.h>
#include <math.h>

// SphericalSpectralTimeConv: L_in=L_out=128 (NT=128 thetas, NPHI=255 phis),
// Lf=64 (NM=64 m>=0, NJ=127 signed m), Cin=Cout=64, T=256.
//
// ws layout (float offsets). G overlaps FMW/TC/FLM/RT which are dead by the
// time the g-phase runs. Total = 3,678,720 floats = 14.7 MB.
// BAR: one uint in the 2-float gap between TW (ends 524926) and FMW (524928).
#define PI_D 3.14159265358979323846
static const size_t OFF_P   = 0;         // float  [64m][64l][128t]
static const size_t OFF_W   = 524288;    // float  [128]
static const size_t OFF_TW  = 524416;    // float2 [255]
static const size_t OFF_BAR = 524926;    // uint   [1] grid-barrier counter
static const size_t OFF_FMW = 524928;    // float2 [64m][128t][64c]
static const size_t OFF_TC  = 1573504;   // float2 [64l][127j]
static const size_t OFF_FLM = 1589760;   // float2 [64l][64m][64c]
static const size_t OFF_RT  = 2114048;   // float2 [64l][64o][64i]
static const size_t OFF_FO  = 2638336;   // float2 [64l][127j][64o]
static const size_t OFF_G   = 524928;    // float2 [128t][127j][64o] (overlay)
static const size_t WS_FLOATS = 3678720;

#define NBLK_TAIL 512

// K_PREP: one launch, 3 independent roles.
//   blocks [0,128):   quadrature weights w[t] (t = bid) + tw table (block 0)
//   blocks [128,192): Legendre P[m][l][t] (m = bid-128, t = tid<128)
//   blocks [192,700): t_c reduction, 16 (l,j) pairs per block
__global__ __launch_bounds__(256) void k_prep(float* __restrict__ w, float2* __restrict__ tw,
                                              float* __restrict__ P,
                                              const float* __restrict__ te, const float* __restrict__ Ar,
                                              const float* __restrict__ Ai, float2* __restrict__ tc,
                                              unsigned* __restrict__ bar) {
  __shared__ double redd[256];
  __shared__ float2 red2[4];
  int bid = blockIdx.x, tid = threadIdx.x;

  if (bid < 128) {
    // ---- tables role ----
    int t = bid;
    if (t == 0 && tid == 0) bar[0] = 0u;   // zero grid-barrier for k_tail
    if (t == 0 && tid < 255) {
      double a = 2.0 * PI_D * tid / 255.0;
      tw[tid] = make_float2((float)cos(a), (float)sin(a));
    }
    double term = 0.0;
    if (tid < 255) {
      int m = tid - 127;
      double br = 0.0, bi = 0.0; bool active = true;
      if (m == 1) bi = PI_D / 2.0;
      else if (m == -1) bi = -PI_D / 2.0;
      else if ((m & 1) == 0) br = 2.0 / (1.0 - (double)m * (double)m);
      else active = false;
      if (active) {
        double md = (double)m;
        double ca = cos(PI_D * md / 255.0), sa = -sin(PI_D * md / 255.0);   // e^{-i pi m/255}
        double wr = br * ca - bi * sa;
        double wi = br * sa + bi * ca;
        double a1 = 2.0 * PI_D * md * t / 255.0;
        double fr = cos(a1), fi = -sin(a1);                                  // e^{-2pi i m t/255}
        if (t < 127) {
          double a2 = 2.0 * PI_D * md * (t + 1) / 255.0;
          fr += cos(a2); fi += sin(a2);                                      // + e^{+2pi i m (t+1)/255}
        }
        term = wr * fr - wi * fi;
      }
    }
    redd[tid] = term;
    __syncthreads();
    for (int off = 128; off; off >>= 1) {
      if (tid < off) redd[tid] += redd[tid + off];
      __syncthreads();
    }
    if (tid == 0) w[t] = (float)(redd[0] * 2.0 * PI_D / (255.0 * 255.0));
  } else if (bid < 192) {
    // ---- Legendre role ----
    if (tid < 128) {
      int m = bid - 128, t = tid;
      double th = PI_D * (2 * t + 1) / 255.0;
      double ct = cos(th), st = sin(th);
      double pmm = 0.28209479177387814;  // 1/sqrt(4 pi)
      for (int k = 1; k <= m; ++k) pmm *= -sqrt((2.0 * k + 1.0) / (2.0 * k)) * st;
      float* Pm = P + ((size_t)m * 64) * 128;
      Pm[(size_t)m * 128 + t] = (float)pmm;
      if (m + 1 < 64) {
        double p0 = pmm, p1 = sqrt(2.0 * m + 3.0) * ct * pmm;
        Pm[(size_t)(m + 1) * 128 + t] = (float)p1;
        for (int l = m + 2; l < 64; ++l) {
          double ll = (double)l * l, mm = (double)m * m;
          double a = sqrt((4.0 * ll - 1.0) / (ll - mm));
          double b = sqrt((2.0 * l + 1.0) * ((double)(l - 1) * (l - 1) - mm) / ((2.0 * l - 3.0) * (ll - mm)));
          double pl = a * ct * p1 - b * p0;
          Pm[(size_t)l * 128 + t] = (float)pl;
          p0 = p1; p1 = pl;
        }
      }
    }
  } else {
    // ---- tc role: 16 (l*127+j) pairs per block ----
    int b = bid - 192;
    float e = te[tid];
    for (int k = 0; k < 16; ++k) {
      int pair = b * 16 + k;
      float vr = Ar[(size_t)pair * 256 + tid] * e;
      float vi = Ai[(size_t)pair * 256 + tid] * e;
      for (int off = 32; off; off >>= 1) {
        vr += __shfl_down(vr, off);
        vi += __shfl_down(vi, off);
      }
      if ((tid & 63) == 0) red2[tid >> 6] = make_float2(vr, vi);
      __syncthreads();
      if (tid == 0) {
        float2 s = red2[0];
        for (int q = 1; q < 4; ++q) { s.x += red2[q].x; s.y += red2[q].y; }
        tc[pair] = s;
      }
      __syncthreads();
    }
  }
}

// K_FUSED (unchanged from R3, verified): grid-partitioned fusion of the
// forward phi-DFT (VALU-bound) and the Rt contraction (HBM-bound ~2.7 TB/s
// per-CU-MLP wall). Even blocks = DFT role, odd = Rt role.
__global__ __launch_bounds__(256) void k_fused(const float* __restrict__ x, const float* __restrict__ w,
                                               const float2* __restrict__ tw, float2* __restrict__ Fmw,
                                               const float* __restrict__ Rr, const float* __restrict__ Ri,
                                               const float2* __restrict__ tc, float2* __restrict__ Rt) {
  __shared__ union SM {
    float xs[64 * 64];                 // 16 KB (DFT role)
    struct {
      float2 tcs[127];
      float4 redr[256];
      float4 redi[256];
    } rt;                              // ~9.2 KB (Rt role)
  } sm;
  int bid = blockIdx.x;
  int tid = threadIdx.x;
  int id = bid >> 1;

  if ((bid & 1) == 0) {
    // ---------------- DFT role ----------------
    int t = id >> 3, mq = id & 7;
    int c = tid & 63, ms = tid >> 6;
    int m0 = mq * 8 + ms * 2;
    float2 wm0 = tw[m0], wm1 = tw[m0 + 1];
    float cr0 = wm0.x, ci0 = -wm0.y;  // e^{-2pi i m0/255}
    float cr1 = wm1.x, ci1 = -wm1.y;
    float tr0 = 1.f, ti0 = 0.f, tr1 = 1.f, ti1 = 0.f;
    float a0r = 0.f, a0i = 0.f, a1r = 0.f, a1i = 0.f;
    const float* xrow = x + (size_t)t * (255 * 64);
    for (int ch = 0; ch < 4; ++ch) {
      int plen = (ch == 3) ? 63 : 64;
      __syncthreads();
      const float4* src = reinterpret_cast<const float4*>(xrow + ch * 64 * 64);
      int n4 = plen * 16;
      for (int idx = tid; idx < n4; idx += 256)
        reinterpret_cast<float4*>(sm.xs)[idx] = src[idx];
      __syncthreads();
#pragma unroll 4
      for (int p = 0; p < plen; ++p) {
        float xv = sm.xs[p * 64 + c];
        a0r += xv * tr0; a0i += xv * ti0;
        a1r += xv * tr1; a1i += xv * ti1;
        float n0 = tr0 * cr0 - ti0 * ci0; ti0 = tr0 * ci0 + ti0 * cr0; tr0 = n0;
        float n1 = tr1 * cr1 - ti1 * ci1; ti1 = tr1 * ci1 + ti1 * cr1; tr1 = n1;
      }
    }
    float wt = w[t];
    Fmw[((size_t)m0 * 128 + t) * 64 + c] = make_float2(wt * a0r, wt * a0i);
    Fmw[((size_t)(m0 + 1) * 128 + t) * 64 + c] = make_float2(wt * a1r, wt * a1i);
  } else {
    // ---------------- Rt role (v3 body) ----------------
    int l = id >> 4, og = id & 15;
    if (tid < 127) sm.rt.tcs[tid] = tc[l * 127 + tid];
    __syncthreads();
    int slot = tid & 63;   // (o_local, i4) within the wave
    int jq = tid >> 6;     // j-phase 0..3 (one per wave)
    int ic = slot & 15, ol = slot >> 4;
    int o = og * 4 + ol;
    const float* rr = Rr + ((size_t)l * 127) * 4096 + o * 64 + ic * 4;
    const float* ri = Ri + ((size_t)l * 127) * 4096 + o * 64 + ic * 4;
    float4 ar = make_float4(0.f, 0.f, 0.f, 0.f);
    float4 ai = make_float4(0.f, 0.f, 0.f, 0.f);
#pragma unroll 4
    for (int j = jq; j < 127; j += 4) {
      float2 w2 = sm.rt.tcs[j];
      float4 a = *reinterpret_cast<const float4*>(rr + (size_t)j * 4096);
      float4 b = *reinterpret_cast<const float4*>(ri + (size_t)j * 4096);
      ar.x += w2.x * a.x - w2.y * b.x;  ai.x += w2.x * b.x + w2.y * a.x;
      ar.y += w2.x * a.y - w2.y * b.y;  ai.y += w2.x * b.y + w2.y * a.y;
      ar.z += w2.x * a.z - w2.y * b.z;  ai.z += w2.x * b.z + w2.y * a.z;
      ar.w += w2.x * a.w - w2.y * b.w;  ai.w += w2.x * b.w + w2.y * a.w;
    }
    sm.rt.redr[tid] = ar; sm.rt.redi[tid] = ai;
    __syncthreads();
    if (jq == 0) {
#pragma unroll
      for (int q = 1; q < 4; ++q) {
        float4 a = sm.rt.redr[q * 64 + slot];
        float4 b = sm.rt.redi[q * 64 + slot];
        ar.x += a.x; ar.y += a.y; ar.z += a.z; ar.w += a.w;
        ai.x += b.x; ai.y += b.y; ai.z += b.z; ai.w += b.w;
      }
      float4* rt4 = reinterpret_cast<float4*>(Rt);
      size_t base = ((size_t)l * 64 + o) * 32 + ic * 2;   // float4 units (2 complex each)
      rt4[base]     = make_float4(ar.x, ai.x, ar.y, ai.y);
      rt4[base + 1] = make_float4(ar.z, ai.z, ar.w, ai.w);
    }
  }
}

// Device-scope grid barrier (accumulating counter, no reset race).
// Correct across XCDs: __threadfence() = agent-scope fence -> L2 wb/inv;
// spin load is agent-scope acquire (bypasses stale caches).
__device__ __forceinline__ void grid_bar(unsigned* bar, unsigned target) {
  __syncthreads();
  if (threadIdx.x == 0) {
    __threadfence();
    __hip_atomic_fetch_add(bar, 1u, __ATOMIC_ACQ_REL, __HIP_MEMORY_SCOPE_AGENT);
    while (__hip_atomic_load(bar, __ATOMIC_ACQUIRE, __HIP_MEMORY_SCOPE_AGENT) < target)
      __builtin_amdgcn_s_sleep(2);
    __threadfence();
  }
  __syncthreads();
}

// K_TAIL: flm -> flmout -> g -> idft in one persistent launch, 3 grid barriers.
// 512 blocks exactly; __launch_bounds__(256,2) + 49.4 KB LDS union => >=2
// (actually 3) blocks/CU capacity, so all 512 are co-resident (256 CU x 2).
__global__ __launch_bounds__(256, 2) void k_tail(const float* __restrict__ P, const float2* __restrict__ Fmw,
                                                 float2* __restrict__ flm, const float2* __restrict__ Rt,
                                                 float2* __restrict__ fo, float2* __restrict__ G,
                                                 const float2* __restrict__ tw, float* __restrict__ out,
                                                 unsigned* __restrict__ bar) {
  __shared__ union TSM {
    struct { float2 Fs[32][64]; float Ps[8][32]; } flm;        // 33.8 KB
    struct { float2 Rts[64][65]; float2 Fjs[16][64]; } fo;     // 41.5 KB
    struct { float Ps[64][32]; float2 Fos[64][64]; } g;        // 40 KB
    struct { float2 CSs[64][64]; float Ls[64][65]; } idft;     // 48.3 KB
  } sm;
  int bid = blockIdx.x, tid = threadIdx.x;

  // ---------- phase 0: flm[l][m][c] = sum_t P[m][l][t] * Fmw[m][t][c] ----------
  {
    int m = bid >> 3, lq = bid & 7;
    int c = tid & 63, lg = tid >> 6;
    float2 acc[2];
    acc[0] = make_float2(0.f, 0.f);
    acc[1] = make_float2(0.f, 0.f);
    for (int q = 0; q < 4; ++q) {
      __syncthreads();
      for (int idx = tid; idx < 2048; idx += 256) {
        int tt = idx >> 6, cc = idx & 63;
        sm.flm.Fs[tt][cc] = Fmw[((size_t)m * 128 + q * 32 + tt) * 64 + cc];
      }
      {
        int ll = tid >> 5, tt2 = tid & 31;
        int l = m + lq * 8 + ll;
        sm.flm.Ps[ll][tt2] = (l < 64) ? P[((size_t)m * 64 + l) * 128 + q * 32 + tt2] : 0.f;
      }
      __syncthreads();
      int li = lg * 2;
#pragma unroll 8
      for (int tt = 0; tt < 32; ++tt) {
        float2 f = sm.flm.Fs[tt][c];
        float p0 = sm.flm.Ps[li][tt], p1 = sm.flm.Ps[li + 1][tt];
        acc[0].x += p0 * f.x; acc[0].y += p0 * f.y;
        acc[1].x += p1 * f.x; acc[1].y += p1 * f.y;
      }
    }
#pragma unroll
    for (int s = 0; s < 2; ++s) {
      int l = m + lq * 8 + lg * 2 + s;
      if (l < 64) flm[((size_t)l * 64 + m) * 64 + c] = acc[s];
    }
  }
  grid_bar(bar, NBLK_TAIL);

  // ---------- phase 1: fo[l][j][o] = sum_i flm_s[l][j][i] * Rt[l][o][i] ----------
  {
    int l = bid >> 3, jg = bid & 7;
    int o = tid & 63, js = tid >> 6;
    for (int idx = tid; idx < 4096; idx += 256) {
      int oo = idx >> 6, ii = idx & 63;
      sm.fo.Rts[oo][ii] = Rt[((size_t)l * 64 + oo) * 64 + ii];
    }
    for (int idx = tid; idx < 1024; idx += 256) {
      int jl = idx >> 6, ii = idx & 63;
      int j = jg * 16 + jl;
      float2 v = make_float2(0.f, 0.f);
      if (j < 127) {
        int mm = j - 63, am = mm < 0 ? -mm : mm;
        if (l >= am) {
          float2 f = flm[((size_t)l * 64 + am) * 64 + ii];
          if (mm < 0) { float s = (am & 1) ? -1.f : 1.f; v = make_float2(s * f.x, -s * f.y); }
          else v = f;
        }
      }
      sm.fo.Fjs[jl][ii] = v;
    }
    __syncthreads();
    float2 acc[4];
#pragma unroll
    for (int q = 0; q < 4; ++q) acc[q] = make_float2(0.f, 0.f);
    for (int i = 0; i < 64; ++i) {
      float2 r = sm.fo.Rts[o][i];
#pragma unroll
      for (int q = 0; q < 4; ++q) {
        float2 f = sm.fo.Fjs[js * 4 + q][i];
        acc[q].x += f.x * r.x - f.y * r.y;
        acc[q].y += f.x * r.y + f.y * r.x;
      }
    }
#pragma unroll
    for (int q = 0; q < 4; ++q) {
      int j = jg * 16 + js * 4 + q;
      if (j < 127) fo[((size_t)l * 127 + j) * 64 + o] = acc[q];
    }
  }
  grid_bar(bar, 2 * NBLK_TAIL);

  // ---------- phase 2: G[t][j][o] = sgn * sum_{l>=|m|} P[|m|][l][t] * fo[l][j][o] ----------
  if (bid < 508) {
    int j = bid >> 2, tg = bid & 3;   // 32-t strip per block
    int mm = j - 63, am = mm < 0 ? -mm : mm;
    float sgn = (mm < 0 && (am & 1)) ? -1.f : 1.f;
    int o = tid & 63, ts = tid >> 6;
    for (int idx = tid; idx < 2048; idx += 256) {
      int ll = idx >> 5, tt = idx & 31;
      sm.g.Ps[ll][tt] = P[((size_t)am * 64 + ll) * 128 + tg * 32 + tt];
    }
    for (int idx = tid; idx < 4096; idx += 256) {
      int ll = idx >> 6, oo = idx & 63;
      float2 v = fo[((size_t)ll * 127 + j) * 64 + oo];
      sm.g.Fos[ll][oo] = make_float2(sgn * v.x, sgn * v.y);
    }
    __syncthreads();
    float ar[8], ai2[8];
#pragma unroll
    for (int r = 0; r < 8; ++r) { ar[r] = 0.f; ai2[r] = 0.f; }
    for (int l = am; l < 64; ++l) {
      float2 f = sm.g.Fos[l][o];
#pragma unroll
      for (int q = 0; q < 2; ++q) {
        float4 pv = *reinterpret_cast<const float4*>(&sm.g.Ps[l][ts * 8 + q * 4]);
        ar[q * 4 + 0] += pv.x * f.x;  ai2[q * 4 + 0] += pv.x * f.y;
        ar[q * 4 + 1] += pv.y * f.x;  ai2[q * 4 + 1] += pv.y * f.y;
        ar[q * 4 + 2] += pv.z * f.x;  ai2[q * 4 + 2] += pv.z * f.y;
        ar[q * 4 + 3] += pv.w * f.x;  ai2[q * 4 + 3] += pv.w * f.y;
      }
    }
#pragma unroll
    for (int r = 0; r < 8; ++r) {
      int t = tg * 32 + ts * 8 + r;
      G[((size_t)t * 127 + j) * 64 + o] = make_float2(ar[r], ai2[r]);
    }
  }
  grid_bar(bar, 3 * NBLK_TAIL);

  // ---------- phase 3: out[t][p][o] = Re sum_m G[t][m][o] e^{2pi i m p/255} ----------
  {
    int t = bid >> 2, pq = bid & 3;
    int pl = tid & 63, og = tid >> 6;
    for (int idx = tid; idx < 4096; idx += 256) {
      int m = idx >> 6, oo = idx & 63;
      float2 v;
      if (m == 0) {
        float2 g = G[((size_t)t * 127 + 63) * 64 + oo];
        v = make_float2(g.x, 0.f);
      } else {
        float2 gp = G[((size_t)t * 127 + 63 + m) * 64 + oo];
        float2 gm = G[((size_t)t * 127 + 63 - m) * 64 + oo];
        v = make_float2(gp.x + gm.x, gm.y - gp.y);
      }
      sm.idft.CSs[m][oo] = v;
    }
    __syncthreads();
    int p = pq * 64 + pl;
    float2 wp = tw[p < 255 ? p : 0];
    float twr = 1.f, twi = 0.f;
    float acc[16];
#pragma unroll
    for (int r = 0; r < 16; ++r) acc[r] = 0.f;
    int ob = og * 16;
    for (int m = 0; m < 64; ++m) {
#pragma unroll
      for (int q = 0; q < 8; ++q) {
        float4 cs = *reinterpret_cast<const float4*>(&sm.idft.CSs[m][ob + q * 2]);
        acc[q * 2 + 0] += cs.x * twr + cs.y * twi;
        acc[q * 2 + 1] += cs.z * twr + cs.w * twi;
      }
      float nr = twr * wp.x - twi * wp.y;
      twi = twr * wp.y + twi * wp.x;
      twr = nr;
    }
#pragma unroll
    for (int r = 0; r < 16; ++r) sm.idft.Ls[pl][ob + r] = acc[r];
    __syncthreads();
    for (int idx = tid; idx < 4096; idx += 256) {
      int rr = idx >> 6, oo = idx & 63;
      int pg = pq * 64 + rr;
      if (pg < 255) out[((size_t)t * 255 + pg) * 64 + oo] = sm.idft.Ls[rr][oo];
    }
  }
}

extern "C" void kernel_launch(void* const* d_in, const int* in_sizes, int n_in,
                              void* d_out, int out_size, void* d_ws, size_t ws_size,
                              hipStream_t stream) {
  (void)in_sizes; (void)n_in; (void)out_size;
  if (ws_size < WS_FLOATS * sizeof(float)) return;  // ws too small -> visible failure

  const float* x  = (const float*)d_in[0];
  const float* te = (const float*)d_in[1];
  const float* Ar = (const float*)d_in[2];
  const float* Ai = (const float*)d_in[3];
  const float* Rr = (const float*)d_in[4];
  const float* Ri = (const float*)d_in[5];
  float* out = (float*)d_out;

  float* ws = (float*)d_ws;
  float*    P   = ws + OFF_P;
  float*    w   = ws + OFF_W;
  float2*   tw  = (float2*)(ws + OFF_TW);
  unsigned* bar = (unsigned*)(ws + OFF_BAR);
  float2*   Fmw = (float2*)(ws + OFF_FMW);
  float2*   tc  = (float2*)(ws + OFF_TC);
  float2*   flm = (float2*)(ws + OFF_FLM);
  float2*   Rt  = (float2*)(ws + OFF_RT);
  float2*   fo  = (float2*)(ws + OFF_FO);
  float2*   G   = (float2*)(ws + OFF_G);

  k_prep<<<700, 256, 0, stream>>>(w, tw, P, te, Ar, Ai, tc, bar);
  k_fused<<<2048, 256, 0, stream>>>(x, w, tw, Fmw, Rr, Ri, tc, Rt);
  k_tail<<<NBLK_TAIL, 256, 0, stream>>>(P, Fmw, flm, Rt, fo, G, tw, out, bar);
}

// Round 5
// 370.532 us; speedup vs baseline: 1.4665x; 1.4665x over previous
//
#include <hip/hip_runtime.h>
#include <math.h>

// SphericalSpectralTimeConv: L_in=L_out=128 (NT=128 thetas, NPHI=255 phis),
// Lf=64 (NM=64 m>=0, NJ=127 signed m), Cin=Cout=64, T=256.
//
// ws layout (float offsets). G overlaps FMW/TC/FLM/RT which are dead by the
// time k_g runs. Total = 3,678,720 floats = 14.7 MB.
#define PI_D 3.14159265358979323846
static const size_t OFF_P   = 0;         // float  [64m][64l][128t]
static const size_t OFF_W   = 524288;    // float  [128]
static const size_t OFF_TW  = 524416;    // float2 [255]
static const size_t OFF_FMW = 524928;    // float2 [64m][128t][64c]
static const size_t OFF_TC  = 1573504;   // float2 [64l][127j]
static const size_t OFF_FLM = 1589760;   // float2 [64l][64m][64c]
static const size_t OFF_RT  = 2114048;   // float2 [64l][64o][64i]
static const size_t OFF_FO  = 2638336;   // float2 [64l][127j][64o]
static const size_t OFF_G   = 524928;    // float2 [128t][127j][64o] (overlay)
static const size_t WS_FLOATS = 3678720;

typedef float vf4 __attribute__((ext_vector_type(4)));

// K_PREP: one launch, 3 independent roles (verified R4).
//   blocks [0,128):   quadrature weights w[t] (t = bid) + tw table (block 0)
//   blocks [128,192): Legendre P[m][l][t] (m = bid-128, t = tid<128)
//   blocks [192,700): t_c reduction, 16 (l,j) pairs per block
__global__ __launch_bounds__(256) void k_prep(float* __restrict__ w, float2* __restrict__ tw,
                                              float* __restrict__ P,
                                              const float* __restrict__ te, const float* __restrict__ Ar,
                                              const float* __restrict__ Ai, float2* __restrict__ tc) {
  __shared__ double redd[256];
  __shared__ float2 red2[4];
  int bid = blockIdx.x, tid = threadIdx.x;

  if (bid < 128) {
    // ---- tables role ----
    int t = bid;
    if (t == 0 && tid < 255) {
      double a = 2.0 * PI_D * tid / 255.0;
      tw[tid] = make_float2((float)cos(a), (float)sin(a));
    }
    double term = 0.0;
    if (tid < 255) {
      int m = tid - 127;
      double br = 0.0, bi = 0.0; bool active = true;
      if (m == 1) bi = PI_D / 2.0;
      else if (m == -1) bi = -PI_D / 2.0;
      else if ((m & 1) == 0) br = 2.0 / (1.0 - (double)m * (double)m);
      else active = false;
      if (active) {
        double md = (double)m;
        double ca = cos(PI_D * md / 255.0), sa = -sin(PI_D * md / 255.0);   // e^{-i pi m/255}
        double wr = br * ca - bi * sa;
        double wi = br * sa + bi * ca;
        double a1 = 2.0 * PI_D * md * t / 255.0;
        double fr = cos(a1), fi = -sin(a1);                                  // e^{-2pi i m t/255}
        if (t < 127) {
          double a2 = 2.0 * PI_D * md * (t + 1) / 255.0;
          fr += cos(a2); fi += sin(a2);                                      // + e^{+2pi i m (t+1)/255}
        }
        term = wr * fr - wi * fi;
      }
    }
    redd[tid] = term;
    __syncthreads();
    for (int off = 128; off; off >>= 1) {
      if (tid < off) redd[tid] += redd[tid + off];
      __syncthreads();
    }
    if (tid == 0) w[t] = (float)(redd[0] * 2.0 * PI_D / (255.0 * 255.0));
  } else if (bid < 192) {
    // ---- Legendre role ----
    if (tid < 128) {
      int m = bid - 128, t = tid;
      double th = PI_D * (2 * t + 1) / 255.0;
      double ct = cos(th), st = sin(th);
      double pmm = 0.28209479177387814;  // 1/sqrt(4 pi)
      for (int k = 1; k <= m; ++k) pmm *= -sqrt((2.0 * k + 1.0) / (2.0 * k)) * st;
      float* Pm = P + ((size_t)m * 64) * 128;
      Pm[(size_t)m * 128 + t] = (float)pmm;
      if (m + 1 < 64) {
        double p0 = pmm, p1 = sqrt(2.0 * m + 3.0) * ct * pmm;
        Pm[(size_t)(m + 1) * 128 + t] = (float)p1;
        for (int l = m + 2; l < 64; ++l) {
          double ll = (double)l * l, mm = (double)m * m;
          double a = sqrt((4.0 * ll - 1.0) / (ll - mm));
          double b = sqrt((2.0 * l + 1.0) * ((double)(l - 1) * (l - 1) - mm) / ((2.0 * l - 3.0) * (ll - mm)));
          double pl = a * ct * p1 - b * p0;
          Pm[(size_t)l * 128 + t] = (float)pl;
          p0 = p1; p1 = pl;
        }
      }
    }
  } else {
    // ---- tc role: 16 (l*127+j) pairs per block ----
    int b = bid - 192;
    float e = te[tid];
    for (int k = 0; k < 16; ++k) {
      int pair = b * 16 + k;
      float vr = Ar[(size_t)pair * 256 + tid] * e;
      float vi = Ai[(size_t)pair * 256 + tid] * e;
      for (int off = 32; off; off >>= 1) {
        vr += __shfl_down(vr, off);
        vi += __shfl_down(vi, off);
      }
      if ((tid & 63) == 0) red2[tid >> 6] = make_float2(vr, vi);
      __syncthreads();
      if (tid == 0) {
        float2 s = red2[0];
        for (int q = 1; q < 4; ++q) { s.x += red2[q].x; s.y += red2[q].y; }
        tc[pair] = s;
      }
      __syncthreads();
    }
  }
}

// K_FUSED: grid-partitioned fusion of the forward phi-DFT (VALU-bound) and
// the Rt contraction. Even blocks = DFT role, odd = Rt role.
// R5 change: Rr/Ri loads are NON-TEMPORAL. Every Rt variant (R0-R4) capped at
// ~2.7 TB/s combined L3+HBM with FETCH ~130 MB (half of R served by L3 residue
// of the previous iter) -> hypothesis: Infinity-Cache fabric path is the cap.
// R has zero reuse; nt-bypass should stream it from HBM at ~5-6 TB/s.
__global__ __launch_bounds__(256) void k_fused(const float* __restrict__ x, const float* __restrict__ w,
                                               const float2* __restrict__ tw, float2* __restrict__ Fmw,
                                               const float* __restrict__ Rr, const float* __restrict__ Ri,
                                               const float2* __restrict__ tc, float2* __restrict__ Rt) {
  __shared__ union SM {
    float xs[64 * 64];                 // 16 KB (DFT role)
    struct {
      float2 tcs[127];
      float4 redr[256];
      float4 redi[256];
    } rt;                              // ~9.2 KB (Rt role)
  } sm;
  int bid = blockIdx.x;
  int tid = threadIdx.x;
  int id = bid >> 1;

  if ((bid & 1) == 0) {
    // ---------------- DFT role ----------------
    int t = id >> 3, mq = id & 7;
    int c = tid & 63, ms = tid >> 6;
    int m0 = mq * 8 + ms * 2;
    float2 wm0 = tw[m0], wm1 = tw[m0 + 1];
    float cr0 = wm0.x, ci0 = -wm0.y;  // e^{-2pi i m0/255}
    float cr1 = wm1.x, ci1 = -wm1.y;
    float tr0 = 1.f, ti0 = 0.f, tr1 = 1.f, ti1 = 0.f;
    float a0r = 0.f, a0i = 0.f, a1r = 0.f, a1i = 0.f;
    const float* xrow = x + (size_t)t * (255 * 64);
    for (int ch = 0; ch < 4; ++ch) {
      int plen = (ch == 3) ? 63 : 64;
      __syncthreads();
      const float4* src = reinterpret_cast<const float4*>(xrow + ch * 64 * 64);
      int n4 = plen * 16;
      for (int idx = tid; idx < n4; idx += 256)
        reinterpret_cast<float4*>(sm.xs)[idx] = src[idx];
      __syncthreads();
#pragma unroll 4
      for (int p = 0; p < plen; ++p) {
        float xv = sm.xs[p * 64 + c];
        a0r += xv * tr0; a0i += xv * ti0;
        a1r += xv * tr1; a1i += xv * ti1;
        float n0 = tr0 * cr0 - ti0 * ci0; ti0 = tr0 * ci0 + ti0 * cr0; tr0 = n0;
        float n1 = tr1 * cr1 - ti1 * ci1; ti1 = tr1 * ci1 + ti1 * cr1; tr1 = n1;
      }
    }
    float wt = w[t];
    Fmw[((size_t)m0 * 128 + t) * 64 + c] = make_float2(wt * a0r, wt * a0i);
    Fmw[((size_t)(m0 + 1) * 128 + t) * 64 + c] = make_float2(wt * a1r, wt * a1i);
  } else {
    // ---------------- Rt role (v3 body + nt loads) ----------------
    int l = id >> 4, og = id & 15;
    if (tid < 127) sm.rt.tcs[tid] = tc[l * 127 + tid];
    __syncthreads();
    int slot = tid & 63;   // (o_local, i4) within the wave
    int jq = tid >> 6;     // j-phase 0..3 (one per wave)
    int ic = slot & 15, ol = slot >> 4;
    int o = og * 4 + ol;
    const float* rr = Rr + ((size_t)l * 127) * 4096 + o * 64 + ic * 4;
    const float* ri = Ri + ((size_t)l * 127) * 4096 + o * 64 + ic * 4;
    float4 ar = make_float4(0.f, 0.f, 0.f, 0.f);
    float4 ai = make_float4(0.f, 0.f, 0.f, 0.f);
#pragma unroll 4
    for (int j = jq; j < 127; j += 4) {
      float2 w2 = sm.rt.tcs[j];
      vf4 a = __builtin_nontemporal_load(reinterpret_cast<const vf4*>(rr + (size_t)j * 4096));
      vf4 b = __builtin_nontemporal_load(reinterpret_cast<const vf4*>(ri + (size_t)j * 4096));
      ar.x += w2.x * a.x - w2.y * b.x;  ai.x += w2.x * b.x + w2.y * a.x;
      ar.y += w2.x * a.y - w2.y * b.y;  ai.y += w2.x * b.y + w2.y * a.y;
      ar.z += w2.x * a.z - w2.y * b.z;  ai.z += w2.x * b.z + w2.y * a.z;
      ar.w += w2.x * a.w - w2.y * b.w;  ai.w += w2.x * b.w + w2.y * a.w;
    }
    sm.rt.redr[tid] = ar; sm.rt.redi[tid] = ai;
    __syncthreads();
    if (jq == 0) {
#pragma unroll
      for (int q = 1; q < 4; ++q) {
        float4 a = sm.rt.redr[q * 64 + slot];
        float4 b = sm.rt.redi[q * 64 + slot];
        ar.x += a.x; ar.y += a.y; ar.z += a.z; ar.w += a.w;
        ai.x += b.x; ai.y += b.y; ai.z += b.z; ai.w += b.w;
      }
      float4* rt4 = reinterpret_cast<float4*>(Rt);
      size_t base = ((size_t)l * 64 + o) * 32 + ic * 2;   // float4 units (2 complex each)
      rt4[base]     = make_float4(ar.x, ai.x, ar.y, ai.y);
      rt4[base + 1] = make_float4(ar.z, ai.z, ar.w, ai.w);
    }
  }
}

// K5 v2: flm[l][m][c] = sum_t P[m][l][t] * Fmw[m][t][c].
// grid (m=64, lq=8), block (c64 x lg4), 2 l per thread, P staged in LDS,
// 32-t quarters -> 33 KB LDS, 2 blocks/CU.
__global__ __launch_bounds__(256) void k_flm(const float* __restrict__ P, const float2* __restrict__ Fmw,
                                             float2* __restrict__ flm) {
  int m = blockIdx.x, lq = blockIdx.y;
  int tid = threadIdx.x;
  int c = tid & 63, lg = tid >> 6;
  __shared__ float2 Fs[32][64];  // 32 KB
  __shared__ float Ps[8][32];    // 1 KB
  float2 acc[2];
  acc[0] = make_float2(0.f, 0.f);
  acc[1] = make_float2(0.f, 0.f);
  for (int q = 0; q < 4; ++q) {
    __syncthreads();
    for (int idx = tid; idx < 2048; idx += 256) {
      int tt = idx >> 6, cc = idx & 63;
      Fs[tt][cc] = Fmw[((size_t)m * 128 + q * 32 + tt) * 64 + cc];
    }
    {
      int ll = tid >> 5, tt2 = tid & 31;
      int l = m + lq * 8 + ll;
      Ps[ll][tt2] = (l < 64) ? P[((size_t)m * 64 + l) * 128 + q * 32 + tt2] : 0.f;
    }
    __syncthreads();
    int li = lg * 2;
#pragma unroll 8
    for (int tt = 0; tt < 32; ++tt) {
      float2 f = Fs[tt][c];
      float p0 = Ps[li][tt], p1 = Ps[li + 1][tt];
      acc[0].x += p0 * f.x; acc[0].y += p0 * f.y;
      acc[1].x += p1 * f.x; acc[1].y += p1 * f.y;
    }
  }
#pragma unroll
  for (int s = 0; s < 2; ++s) {
    int l = m + lq * 8 + lg * 2 + s;
    if (l < 64) flm[((size_t)l * 64 + m) * 64 + c] = acc[s];
  }
}

// K6: flm_out[l][j][o] = sum_i flm_signed[l][j][i] * Rt[l][o][i] (complex*complex).
__global__ __launch_bounds__(256) void k_flmout(const float2* __restrict__ flm, const float2* __restrict__ Rt,
                                                float2* __restrict__ fo) {
  int l = blockIdx.x, jg = blockIdx.y;
  int o = threadIdx.x & 63, js = threadIdx.x >> 6;
  __shared__ float2 Rts[64][65];
  __shared__ float2 Fjs[16][64];
  for (int idx = threadIdx.x; idx < 4096; idx += 256) {
    int oo = idx >> 6, ii = idx & 63;
    Rts[oo][ii] = Rt[((size_t)l * 64 + oo) * 64 + ii];
  }
  for (int idx = threadIdx.x; idx < 1024; idx += 256) {
    int jl = idx >> 6, ii = idx & 63;
    int j = jg * 16 + jl;
    float2 v = make_float2(0.f, 0.f);
    if (j < 127) {
      int mm = j - 63, am = mm < 0 ? -mm : mm;
      if (l >= am) {
        float2 f = flm[((size_t)l * 64 + am) * 64 + ii];
        if (mm < 0) { float s = (am & 1) ? -1.f : 1.f; v = make_float2(s * f.x, -s * f.y); }
        else v = f;
      }
    }
    Fjs[jl][ii] = v;
  }
  __syncthreads();
  float2 acc[4];
#pragma unroll
  for (int q = 0; q < 4; ++q) acc[q] = make_float2(0.f, 0.f);
  for (int i = 0; i < 64; ++i) {
    float2 r = Rts[o][i];
#pragma unroll
    for (int q = 0; q < 4; ++q) {
      float2 f = Fjs[js * 4 + q][i];
      acc[q].x += f.x * r.x - f.y * r.y;
      acc[q].y += f.x * r.y + f.y * r.x;
    }
  }
#pragma unroll
  for (int q = 0; q < 4; ++q) {
    int j = jg * 16 + js * 4 + q;
    if (j < 127) fo[((size_t)l * 127 + j) * 64 + o] = acc[q];
  }
}

// K7: G[t][j][o] = sgn * sum_{l>=|m|} P[|m|][l][t] * flm_out[l][j][o].
__global__ __launch_bounds__(256) void k_g(const float* __restrict__ P, const float2* __restrict__ fo,
                                           float2* __restrict__ G) {
  int j = blockIdx.x, tg = blockIdx.y;
  int mm = j - 63, am = mm < 0 ? -mm : mm;
  float sgn = (mm < 0 && (am & 1)) ? -1.f : 1.f;
  int o = threadIdx.x & 63, ts = threadIdx.x >> 6;
  __shared__ float Ps[64][64];
  __shared__ float2 Fos[64][64];
  for (int idx = threadIdx.x; idx < 4096; idx += 256) {
    int ll = idx >> 6, tt = idx & 63;
    Ps[ll][tt] = P[((size_t)am * 64 + ll) * 128 + tg * 64 + tt];
  }
  for (int idx = threadIdx.x; idx < 4096; idx += 256) {
    int ll = idx >> 6, oo = idx & 63;
    float2 v = fo[((size_t)ll * 127 + j) * 64 + oo];
    Fos[ll][oo] = make_float2(sgn * v.x, sgn * v.y);
  }
  __syncthreads();
  float ar[16], ai2[16];
#pragma unroll
  for (int r = 0; r < 16; ++r) { ar[r] = 0.f; ai2[r] = 0.f; }
  for (int l = am; l < 64; ++l) {
    float2 f = Fos[l][o];
#pragma unroll
    for (int q = 0; q < 4; ++q) {
      float4 pv = *reinterpret_cast<const float4*>(&Ps[l][ts * 16 + q * 4]);
      ar[q * 4 + 0] += pv.x * f.x;  ai2[q * 4 + 0] += pv.x * f.y;
      ar[q * 4 + 1] += pv.y * f.x;  ai2[q * 4 + 1] += pv.y * f.y;
      ar[q * 4 + 2] += pv.z * f.x;  ai2[q * 4 + 2] += pv.z * f.y;
      ar[q * 4 + 3] += pv.w * f.x;  ai2[q * 4 + 3] += pv.w * f.y;
    }
  }
#pragma unroll
  for (int r = 0; r < 16; ++r) {
    int t = tg * 64 + ts * 16 + r;
    G[((size_t)t * 127 + j) * 64 + o] = make_float2(ar[r], ai2[r]);
  }
}

// K8: out[t][p][o] = Re sum_m G[t][m][o] e^{2pi i m p/255} via cos/sin split.
__global__ __launch_bounds__(256) void k_idft(const float2* __restrict__ G, const float2* __restrict__ tw,
                                              float* __restrict__ out) {
  int t = blockIdx.x, pq = blockIdx.y;
  int pl = threadIdx.x & 63, og = threadIdx.x >> 6;
  __shared__ __align__(16) unsigned char smem[65536];
  float2 (*CSs)[64] = reinterpret_cast<float2(*)[64]>(smem);
  float (*Ls)[65] = reinterpret_cast<float(*)[65]>(smem);  // aliased after resync
  for (int idx = threadIdx.x; idx < 4096; idx += 256) {
    int m = idx >> 6, oo = idx & 63;
    float2 v;
    if (m == 0) {
      float2 g = G[((size_t)t * 127 + 63) * 64 + oo];
      v = make_float2(g.x, 0.f);
    } else {
      float2 gp = G[((size_t)t * 127 + 63 + m) * 64 + oo];
      float2 gm = G[((size_t)t * 127 + 63 - m) * 64 + oo];
      v = make_float2(gp.x + gm.x, gm.y - gp.y);
    }
    CSs[m][oo] = v;
  }
  __syncthreads();
  int p = pq * 64 + pl;
  float2 wp = tw[p < 255 ? p : 0];
  float twr = 1.f, twi = 0.f;
  float acc[16];
#pragma unroll
  for (int r = 0; r < 16; ++r) acc[r] = 0.f;
  int ob = og * 16;
  for (int m = 0; m < 64; ++m) {
#pragma unroll
    for (int q = 0; q < 8; ++q) {
      float4 cs = *reinterpret_cast<const float4*>(&CSs[m][ob + q * 2]);
      acc[q * 2 + 0] += cs.x * twr + cs.y * twi;
      acc[q * 2 + 1] += cs.z * twr + cs.w * twi;
    }
    float nr = twr * wp.x - twi * wp.y;
    twi = twr * wp.y + twi * wp.x;
    twr = nr;
  }
  __syncthreads();
#pragma unroll
  for (int r = 0; r < 16; ++r) Ls[pl][ob + r] = acc[r];
  __syncthreads();
  for (int idx = threadIdx.x; idx < 4096; idx += 256) {
    int rr = idx >> 6, oo = idx & 63;
    int pg = pq * 64 + rr;
    if (pg < 255) out[((size_t)t * 255 + pg) * 64 + oo] = Ls[rr][oo];
  }
}

extern "C" void kernel_launch(void* const* d_in, const int* in_sizes, int n_in,
                              void* d_out, int out_size, void* d_ws, size_t ws_size,
                              hipStream_t stream) {
  (void)in_sizes; (void)n_in; (void)out_size;
  if (ws_size < WS_FLOATS * sizeof(float)) return;  // ws too small -> visible failure

  const float* x  = (const float*)d_in[0];
  const float* te = (const float*)d_in[1];
  const float* Ar = (const float*)d_in[2];
  const float* Ai = (const float*)d_in[3];
  const float* Rr = (const float*)d_in[4];
  const float* Ri = (const float*)d_in[5];
  float* out = (float*)d_out;

  float* ws = (float*)d_ws;
  float*  P   = ws + OFF_P;
  float*  w   = ws + OFF_W;
  float2* tw  = (float2*)(ws + OFF_TW);
  float2* Fmw = (float2*)(ws + OFF_FMW);
  float2* tc  = (float2*)(ws + OFF_TC);
  float2* flm = (float2*)(ws + OFF_FLM);
  float2* Rt  = (float2*)(ws + OFF_RT);
  float2* fo  = (float2*)(ws + OFF_FO);
  float2* G   = (float2*)(ws + OFF_G);

  k_prep<<<700, 256, 0, stream>>>(w, tw, P, te, Ar, Ai, tc);
  k_fused<<<2048, 256, 0, stream>>>(x, w, tw, Fmw, Rr, Ri, tc, Rt);
  k_flm<<<dim3(64, 8), 256, 0, stream>>>(P, Fmw, flm);
  k_flmout<<<dim3(64, 8), 256, 0, stream>>>(flm, Rt, fo);
  k_g<<<dim3(127, 2), 256, 0, stream>>>(P, fo, G);
  k_idft<<<dim3(128, 4), 256, 0, stream>>>(G, tw, out);
}

// Round 6
// 367.449 us; speedup vs baseline: 1.4788x; 1.0084x over previous
//
#include <hip/hip_runtime.h>
#include <math.h>

// SphericalSpectralTimeConv: L_in=L_out=128 (NT=128 thetas, NPHI=255 phis),
// Lf=64 (NM=64 m>=0, NJ=127 signed m), Cin=Cout=64, T=256.
//
// ws layout (float offsets). G overlaps FMW/TC/FLM/RT which are dead by the
// time k_g runs. Total = 3,678,720 floats = 14.7 MB.
#define PI_D 3.14159265358979323846
static const size_t OFF_P   = 0;         // float  [64m][64l][128t]
static const size_t OFF_W   = 524288;    // float  [128]
static const size_t OFF_TW  = 524416;    // float2 [255]
static const size_t OFF_FMW = 524928;    // float2 [64m][128t][64c]
static const size_t OFF_TC  = 1573504;   // float2 [64l][127j]
static const size_t OFF_FLM = 1589760;   // float2 [64l][64m][64c]
static const size_t OFF_RT  = 2114048;   // float2 [64l][64o][64i]
static const size_t OFF_FO  = 2638336;   // float2 [64l][127j][64o]
static const size_t OFF_G   = 524928;    // float2 [128t][127j][64o] (overlay)
static const size_t WS_FLOATS = 3678720;

typedef float vf4 __attribute__((ext_vector_type(4)));

// K_PREP: one launch, 3 independent roles (verified R4/R5).
//   blocks [0,128):   quadrature weights w[t] (t = bid) + tw table (block 0)
//   blocks [128,192): Legendre P[m][l][t] (m = bid-128, t = tid<128)
//   blocks [192,700): t_c reduction, 16 (l,j) pairs per block
__global__ __launch_bounds__(256) void k_prep(float* __restrict__ w, float2* __restrict__ tw,
                                              float* __restrict__ P,
                                              const float* __restrict__ te, const float* __restrict__ Ar,
                                              const float* __restrict__ Ai, float2* __restrict__ tc) {
  __shared__ double redd[256];
  __shared__ float2 red2[4];
  int bid = blockIdx.x, tid = threadIdx.x;

  if (bid < 128) {
    // ---- tables role ----
    int t = bid;
    if (t == 0 && tid < 255) {
      double a = 2.0 * PI_D * tid / 255.0;
      tw[tid] = make_float2((float)cos(a), (float)sin(a));
    }
    double term = 0.0;
    if (tid < 255) {
      int m = tid - 127;
      double br = 0.0, bi = 0.0; bool active = true;
      if (m == 1) bi = PI_D / 2.0;
      else if (m == -1) bi = -PI_D / 2.0;
      else if ((m & 1) == 0) br = 2.0 / (1.0 - (double)m * (double)m);
      else active = false;
      if (active) {
        double md = (double)m;
        double ca = cos(PI_D * md / 255.0), sa = -sin(PI_D * md / 255.0);   // e^{-i pi m/255}
        double wr = br * ca - bi * sa;
        double wi = br * sa + bi * ca;
        double a1 = 2.0 * PI_D * md * t / 255.0;
        double fr = cos(a1), fi = -sin(a1);                                  // e^{-2pi i m t/255}
        if (t < 127) {
          double a2 = 2.0 * PI_D * md * (t + 1) / 255.0;
          fr += cos(a2); fi += sin(a2);                                      // + e^{+2pi i m (t+1)/255}
        }
        term = wr * fr - wi * fi;
      }
    }
    redd[tid] = term;
    __syncthreads();
    for (int off = 128; off; off >>= 1) {
      if (tid < off) redd[tid] += redd[tid + off];
      __syncthreads();
    }
    if (tid == 0) w[t] = (float)(redd[0] * 2.0 * PI_D / (255.0 * 255.0));
  } else if (bid < 192) {
    // ---- Legendre role ----
    if (tid < 128) {
      int m = bid - 128, t = tid;
      double th = PI_D * (2 * t + 1) / 255.0;
      double ct = cos(th), st = sin(th);
      double pmm = 0.28209479177387814;  // 1/sqrt(4 pi)
      for (int k = 1; k <= m; ++k) pmm *= -sqrt((2.0 * k + 1.0) / (2.0 * k)) * st;
      float* Pm = P + ((size_t)m * 64) * 128;
      Pm[(size_t)m * 128 + t] = (float)pmm;
      if (m + 1 < 64) {
        double p0 = pmm, p1 = sqrt(2.0 * m + 3.0) * ct * pmm;
        Pm[(size_t)(m + 1) * 128 + t] = (float)p1;
        for (int l = m + 2; l < 64; ++l) {
          double ll = (double)l * l, mm = (double)m * m;
          double a = sqrt((4.0 * ll - 1.0) / (ll - mm));
          double b = sqrt((2.0 * l + 1.0) * ((double)(l - 1) * (l - 1) - mm) / ((2.0 * l - 3.0) * (ll - mm)));
          double pl = a * ct * p1 - b * p0;
          Pm[(size_t)l * 128 + t] = (float)pl;
          p0 = p1; p1 = pl;
        }
      }
    }
  } else {
    // ---- tc role: 16 (l*127+j) pairs per block ----
    int b = bid - 192;
    float e = te[tid];
    for (int k = 0; k < 16; ++k) {
      int pair = b * 16 + k;
      float vr = Ar[(size_t)pair * 256 + tid] * e;
      float vi = Ai[(size_t)pair * 256 + tid] * e;
      for (int off = 32; off; off >>= 1) {
        vr += __shfl_down(vr, off);
        vi += __shfl_down(vi, off);
      }
      if ((tid & 63) == 0) red2[tid >> 6] = make_float2(vr, vi);
      __syncthreads();
      if (tid == 0) {
        float2 s = red2[0];
        for (int q = 1; q < 4; ++q) { s.x += red2[q].x; s.y += red2[q].y; }
        tc[pair] = s;
      }
      __syncthreads();
    }
  }
}

// K_FUSED: grid-partitioned fusion of the forward phi-DFT (VALU-bound) and
// the Rt contraction. Even blocks = DFT role, odd = Rt role.
// R5: nt loads on Rr/Ri broke the 2.7 TB/s Infinity-Cache-path wall
// (fused 110 -> <77 us). R6: unroll 8 on the j-loop -> 16 nt loads
// (256 B) in flight per thread, deeper queue vs ~900cy HBM latency.
__global__ __launch_bounds__(256) void k_fused(const float* __restrict__ x, const float* __restrict__ w,
                                               const float2* __restrict__ tw, float2* __restrict__ Fmw,
                                               const float* __restrict__ Rr, const float* __restrict__ Ri,
                                               const float2* __restrict__ tc, float2* __restrict__ Rt) {
  __shared__ union SM {
    float xs[64 * 64];                 // 16 KB (DFT role)
    struct {
      float2 tcs[127];
      float4 redr[256];
      float4 redi[256];
    } rt;                              // ~9.2 KB (Rt role)
  } sm;
  int bid = blockIdx.x;
  int tid = threadIdx.x;
  int id = bid >> 1;

  if ((bid & 1) == 0) {
    // ---------------- DFT role ----------------
    int t = id >> 3, mq = id & 7;
    int c = tid & 63, ms = tid >> 6;
    int m0 = mq * 8 + ms * 2;
    float2 wm0 = tw[m0], wm1 = tw[m0 + 1];
    float cr0 = wm0.x, ci0 = -wm0.y;  // e^{-2pi i m0/255}
    float cr1 = wm1.x, ci1 = -wm1.y;
    float tr0 = 1.f, ti0 = 0.f, tr1 = 1.f, ti1 = 0.f;
    float a0r = 0.f, a0i = 0.f, a1r = 0.f, a1i = 0.f;
    const float* xrow = x + (size_t)t * (255 * 64);
    for (int ch = 0; ch < 4; ++ch) {
      int plen = (ch == 3) ? 63 : 64;
      __syncthreads();
      const float4* src = reinterpret_cast<const float4*>(xrow + ch * 64 * 64);
      int n4 = plen * 16;
      for (int idx = tid; idx < n4; idx += 256)
        reinterpret_cast<float4*>(sm.xs)[idx] = src[idx];
      __syncthreads();
#pragma unroll 4
      for (int p = 0; p < plen; ++p) {
        float xv = sm.xs[p * 64 + c];
        a0r += xv * tr0; a0i += xv * ti0;
        a1r += xv * tr1; a1i += xv * ti1;
        float n0 = tr0 * cr0 - ti0 * ci0; ti0 = tr0 * ci0 + ti0 * cr0; tr0 = n0;
        float n1 = tr1 * cr1 - ti1 * ci1; ti1 = tr1 * ci1 + ti1 * cr1; tr1 = n1;
      }
    }
    float wt = w[t];
    Fmw[((size_t)m0 * 128 + t) * 64 + c] = make_float2(wt * a0r, wt * a0i);
    Fmw[((size_t)(m0 + 1) * 128 + t) * 64 + c] = make_float2(wt * a1r, wt * a1i);
  } else {
    // ---------------- Rt role (v3 body + nt loads, unroll 8) ----------------
    int l = id >> 4, og = id & 15;
    if (tid < 127) sm.rt.tcs[tid] = tc[l * 127 + tid];
    __syncthreads();
    int slot = tid & 63;   // (o_local, i4) within the wave
    int jq = tid >> 6;     // j-phase 0..3 (one per wave)
    int ic = slot & 15, ol = slot >> 4;
    int o = og * 4 + ol;
    const float* rr = Rr + ((size_t)l * 127) * 4096 + o * 64 + ic * 4;
    const float* ri = Ri + ((size_t)l * 127) * 4096 + o * 64 + ic * 4;
    float4 ar = make_float4(0.f, 0.f, 0.f, 0.f);
    float4 ai = make_float4(0.f, 0.f, 0.f, 0.f);
#pragma unroll 8
    for (int j = jq; j < 127; j += 4) {
      float2 w2 = sm.rt.tcs[j];
      vf4 a = __builtin_nontemporal_load(reinterpret_cast<const vf4*>(rr + (size_t)j * 4096));
      vf4 b = __builtin_nontemporal_load(reinterpret_cast<const vf4*>(ri + (size_t)j * 4096));
      ar.x += w2.x * a.x - w2.y * b.x;  ai.x += w2.x * b.x + w2.y * a.x;
      ar.y += w2.x * a.y - w2.y * b.y;  ai.y += w2.x * b.y + w2.y * a.y;
      ar.z += w2.x * a.z - w2.y * b.z;  ai.z += w2.x * b.z + w2.y * a.z;
      ar.w += w2.x * a.w - w2.y * b.w;  ai.w += w2.x * b.w + w2.y * a.w;
    }
    sm.rt.redr[tid] = ar; sm.rt.redi[tid] = ai;
    __syncthreads();
    if (jq == 0) {
#pragma unroll
      for (int q = 1; q < 4; ++q) {
        float4 a = sm.rt.redr[q * 64 + slot];
        float4 b = sm.rt.redi[q * 64 + slot];
        ar.x += a.x; ar.y += a.y; ar.z += a.z; ar.w += a.w;
        ai.x += b.x; ai.y += b.y; ai.z += b.z; ai.w += b.w;
      }
      float4* rt4 = reinterpret_cast<float4*>(Rt);
      size_t base = ((size_t)l * 64 + o) * 32 + ic * 2;   // float4 units (2 complex each)
      rt4[base]     = make_float4(ar.x, ai.x, ar.y, ai.y);
      rt4[base + 1] = make_float4(ar.z, ai.z, ar.w, ai.w);
    }
  }
}

// K5 v2: flm[l][m][c] = sum_t P[m][l][t] * Fmw[m][t][c].
// grid (m=64, lq=8), block (c64 x lg4), 2 l per thread, P staged in LDS,
// 32-t quarters -> 33 KB LDS, 2 blocks/CU.
__global__ __launch_bounds__(256) void k_flm(const float* __restrict__ P, const float2* __restrict__ Fmw,
                                             float2* __restrict__ flm) {
  int m = blockIdx.x, lq = blockIdx.y;
  int tid = threadIdx.x;
  int c = tid & 63, lg = tid >> 6;
  __shared__ float2 Fs[32][64];  // 32 KB
  __shared__ float Ps[8][32];    // 1 KB
  float2 acc[2];
  acc[0] = make_float2(0.f, 0.f);
  acc[1] = make_float2(0.f, 0.f);
  for (int q = 0; q < 4; ++q) {
    __syncthreads();
    for (int idx = tid; idx < 2048; idx += 256) {
      int tt = idx >> 6, cc = idx & 63;
      Fs[tt][cc] = Fmw[((size_t)m * 128 + q * 32 + tt) * 64 + cc];
    }
    {
      int ll = tid >> 5, tt2 = tid & 31;
      int l = m + lq * 8 + ll;
      Ps[ll][tt2] = (l < 64) ? P[((size_t)m * 64 + l) * 128 + q * 32 + tt2] : 0.f;
    }
    __syncthreads();
    int li = lg * 2;
#pragma unroll 8
    for (int tt = 0; tt < 32; ++tt) {
      float2 f = Fs[tt][c];
      float p0 = Ps[li][tt], p1 = Ps[li + 1][tt];
      acc[0].x += p0 * f.x; acc[0].y += p0 * f.y;
      acc[1].x += p1 * f.x; acc[1].y += p1 * f.y;
    }
  }
#pragma unroll
  for (int s = 0; s < 2; ++s) {
    int l = m + lq * 8 + lg * 2 + s;
    if (l < 64) flm[((size_t)l * 64 + m) * 64 + c] = acc[s];
  }
}

// K6: flm_out[l][j][o] = sum_i flm_signed[l][j][i] * Rt[l][o][i] (complex*complex).
__global__ __launch_bounds__(256) void k_flmout(const float2* __restrict__ flm, const float2* __restrict__ Rt,
                                                float2* __restrict__ fo) {
  int l = blockIdx.x, jg = blockIdx.y;
  int o = threadIdx.x & 63, js = threadIdx.x >> 6;
  __shared__ float2 Rts[64][65];
  __shared__ float2 Fjs[16][64];
  for (int idx = threadIdx.x; idx < 4096; idx += 256) {
    int oo = idx >> 6, ii = idx & 63;
    Rts[oo][ii] = Rt[((size_t)l * 64 + oo) * 64 + ii];
  }
  for (int idx = threadIdx.x; idx < 1024; idx += 256) {
    int jl = idx >> 6, ii = idx & 63;
    int j = jg * 16 + jl;
    float2 v = make_float2(0.f, 0.f);
    if (j < 127) {
      int mm = j - 63, am = mm < 0 ? -mm : mm;
      if (l >= am) {
        float2 f = flm[((size_t)l * 64 + am) * 64 + ii];
        if (mm < 0) { float s = (am & 1) ? -1.f : 1.f; v = make_float2(s * f.x, -s * f.y); }
        else v = f;
      }
    }
    Fjs[jl][ii] = v;
  }
  __syncthreads();
  float2 acc[4];
#pragma unroll
  for (int q = 0; q < 4; ++q) acc[q] = make_float2(0.f, 0.f);
  for (int i = 0; i < 64; ++i) {
    float2 r = Rts[o][i];
#pragma unroll
    for (int q = 0; q < 4; ++q) {
      float2 f = Fjs[js * 4 + q][i];
      acc[q].x += f.x * r.x - f.y * r.y;
      acc[q].y += f.x * r.y + f.y * r.x;
    }
  }
#pragma unroll
  for (int q = 0; q < 4; ++q) {
    int j = jg * 16 + js * 4 + q;
    if (j < 127) fo[((size_t)l * 127 + j) * 64 + o] = acc[q];
  }
}

// K7: G[t][j][o] = sgn * sum_{l>=|m|} P[|m|][l][t] * flm_out[l][j][o].
__global__ __launch_bounds__(256) void k_g(const float* __restrict__ P, const float2* __restrict__ fo,
                                           float2* __restrict__ G) {
  int j = blockIdx.x, tg = blockIdx.y;
  int mm = j - 63, am = mm < 0 ? -mm : mm;
  float sgn = (mm < 0 && (am & 1)) ? -1.f : 1.f;
  int o = threadIdx.x & 63, ts = threadIdx.x >> 6;
  __shared__ float Ps[64][64];
  __shared__ float2 Fos[64][64];
  for (int idx = threadIdx.x; idx < 4096; idx += 256) {
    int ll = idx >> 6, tt = idx & 63;
    Ps[ll][tt] = P[((size_t)am * 64 + ll) * 128 + tg * 64 + tt];
  }
  for (int idx = threadIdx.x; idx < 4096; idx += 256) {
    int ll = idx >> 6, oo = idx & 63;
    float2 v = fo[((size_t)ll * 127 + j) * 64 + oo];
    Fos[ll][oo] = make_float2(sgn * v.x, sgn * v.y);
  }
  __syncthreads();
  float ar[16], ai2[16];
#pragma unroll
  for (int r = 0; r < 16; ++r) { ar[r] = 0.f; ai2[r] = 0.f; }
  for (int l = am; l < 64; ++l) {
    float2 f = Fos[l][o];
#pragma unroll
    for (int q = 0; q < 4; ++q) {
      float4 pv = *reinterpret_cast<const float4*>(&Ps[l][ts * 16 + q * 4]);
      ar[q * 4 + 0] += pv.x * f.x;  ai2[q * 4 + 0] += pv.x * f.y;
      ar[q * 4 + 1] += pv.y * f.x;  ai2[q * 4 + 1] += pv.y * f.y;
      ar[q * 4 + 2] += pv.z * f.x;  ai2[q * 4 + 2] += pv.z * f.y;
      ar[q * 4 + 3] += pv.w * f.x;  ai2[q * 4 + 3] += pv.w * f.y;
    }
  }
#pragma unroll
  for (int r = 0; r < 16; ++r) {
    int t = tg * 64 + ts * 16 + r;
    G[((size_t)t * 127 + j) * 64 + o] = make_float2(ar[r], ai2[r]);
  }
}

// K8: out[t][p][o] = Re sum_m G[t][m][o] e^{2pi i m p/255} via cos/sin split.
__global__ __launch_bounds__(256) void k_idft(const float2* __restrict__ G, const float2* __restrict__ tw,
                                              float* __restrict__ out) {
  int t = blockIdx.x, pq = blockIdx.y;
  int pl = threadIdx.x & 63, og = threadIdx.x >> 6;
  __shared__ __align__(16) unsigned char smem[65536];
  float2 (*CSs)[64] = reinterpret_cast<float2(*)[64]>(smem);
  float (*Ls)[65] = reinterpret_cast<float(*)[65]>(smem);  // aliased after resync
  for (int idx = threadIdx.x; idx < 4096; idx += 256) {
    int m = idx >> 6, oo = idx & 63;
    float2 v;
    if (m == 0) {
      float2 g = G[((size_t)t * 127 + 63) * 64 + oo];
      v = make_float2(g.x, 0.f);
    } else {
      float2 gp = G[((size_t)t * 127 + 63 + m) * 64 + oo];
      float2 gm = G[((size_t)t * 127 + 63 - m) * 64 + oo];
      v = make_float2(gp.x + gm.x, gm.y - gp.y);
    }
    CSs[m][oo] = v;
  }
  __syncthreads();
  int p = pq * 64 + pl;
  float2 wp = tw[p < 255 ? p : 0];
  float twr = 1.f, twi = 0.f;
  float acc[16];
#pragma unroll
  for (int r = 0; r < 16; ++r) acc[r] = 0.f;
  int ob = og * 16;
  for (int m = 0; m < 64; ++m) {
#pragma unroll
    for (int q = 0; q < 8; ++q) {
      float4 cs = *reinterpret_cast<const float4*>(&CSs[m][ob + q * 2]);
      acc[q * 2 + 0] += cs.x * twr + cs.y * twi;
      acc[q * 2 + 1] += cs.z * twr + cs.w * twi;
    }
    float nr = twr * wp.x - twi * wp.y;
    twi = twr * wp.y + twi * wp.x;
    twr = nr;
  }
  __syncthreads();
#pragma unroll
  for (int r = 0; r < 16; ++r) Ls[pl][ob + r] = acc[r];
  __syncthreads();
  for (int idx = threadIdx.x; idx < 4096; idx += 256) {
    int rr = idx >> 6, oo = idx & 63;
    int pg = pq * 64 + rr;
    if (pg < 255) out[((size_t)t * 255 + pg) * 64 + oo] = Ls[rr][oo];
  }
}

extern "C" void kernel_launch(void* const* d_in, const int* in_sizes, int n_in,
                              void* d_out, int out_size, void* d_ws, size_t ws_size,
                              hipStream_t stream) {
  (void)in_sizes; (void)n_in; (void)out_size;
  if (ws_size < WS_FLOATS * sizeof(float)) return;  // ws too small -> visible failure

  const float* x  = (const float*)d_in[0];
  const float* te = (const float*)d_in[1];
  const float* Ar = (const float*)d_in[2];
  const float* Ai = (const float*)d_in[3];
  const float* Rr = (const float*)d_in[4];
  const float* Ri = (const float*)d_in[5];
  float* out = (float*)d_out;

  float* ws = (float*)d_ws;
  float*  P   = ws + OFF_P;
  float*  w   = ws + OFF_W;
  float2* tw  = (float2*)(ws + OFF_TW);
  float2* Fmw = (float2*)(ws + OFF_FMW);
  float2* tc  = (float2*)(ws + OFF_TC);
  float2* flm = (float2*)(ws + OFF_FLM);
  float2* Rt  = (float2*)(ws + OFF_RT);
  float2* fo  = (float2*)(ws + OFF_FO);
  float2* G   = (float2*)(ws + OFF_G);

  k_prep<<<700, 256, 0, stream>>>(w, tw, P, te, Ar, Ai, tc);
  k_fused<<<2048, 256, 0, stream>>>(x, w, tw, Fmw, Rr, Ri, tc, Rt);
  k_flm<<<dim3(64, 8), 256, 0, stream>>>(P, Fmw, flm);
  k_flmout<<<dim3(64, 8), 256, 0, stream>>>(flm, Rt, fo);
  k_g<<<dim3(127, 2), 256, 0, stream>>>(P, fo, G);
  k_idft<<<dim3(128, 4), 256, 0, stream>>>(G, tw, out);
}